// Round 8
// baseline (196.097 us; speedup 1.0000x reference)
//
#include <hip/hip_runtime.h>
#include <math.h>

#define BB 32
#define KK 64
#define HH 96
#define WW 128
#define HW (HH*WW)             // 12288
#define MAP_SIZE (BB*KK*HW)    // 25165824
#define NBK (BB*KK)            // 2048
#define TK 64                  // pixels per block tile (1 wave, thread-per-pixel)
#define NTB (HW/TK)            // 192 tiles per image
#define NBLK (BB*NTB)          // 6144 blocks = 24 per CU

// ---------------- Fused kernel: softmax + map write + per-(b,k) reductions ----------
// PHASE-DECORRELATION experiment: 64-px / 1-wave blocks with 16.9 KB LDS -> 8-9
// independent blocks resident per CU (vs 2 before), each with its own read/write
// phase clock and staggered completion. Goal: the memory controllers see a
// continuous MIX of reads and writes instead of GPU-wide 64-KB read-burst /
// write-burst oscillation (suspected cause of the ~2.8 TB/s plateau; fill=6.8,
// copy=6.3 TB/s). Hint config = round-7 winner: PLAIN loads, NT stores.
// Bonus: thread t owns all 64 px of channel t in phase 3 -> no shuffles at all.
// Stride-65 LDS rows: every access pattern is exactly 2 lanes/bank (free).
__global__ __launch_bounds__(64, 2) void fused_k(const float* __restrict__ x,
                                                 float* __restrict__ out,
                                                 double* __restrict__ sxyz) {
    __shared__ float sm[KK][65];   // 16.9 KB; bank(k*65+t) = (k+t)&31 -> 2-way everywhere

    int blk  = blockIdx.x;
    int b    = blk / NTB;
    int tile = blk - b * NTB;
    int t    = threadIdx.x;        // lane == thread (1 wave)
    size_t base = (size_t)b * (KK * HW) + (size_t)tile * TK + t;

    // Phase 1: 64 strided channel loads (PLAIN, 256 B/instr coalesced), exp -> LDS,
    // denominator in the same serial k-order as every passing round (bit-identical).
    float den = 0.f;
    #pragma unroll
    for (int k = 0; k < KK; ++k) {
        float e = __expf(x[base + (size_t)k * HW]);
        sm[k][t] = e;
        den += e;
    }
    float inv = 1.f / den;

    // Phase 2: normalize own column (thread-private LDS: no barrier needed),
    // NT-store the map (streaming write, nothing re-reads it), stage m for phase 3.
    #pragma unroll
    for (int k = 0; k < KK; ++k) {
        float m = sm[k][t] * inv;
        __builtin_nontemporal_store(m, &out[base + (size_t)k * HW]);
        sm[k][t] = m;
    }
    __syncthreads();   // single barrier: make all columns visible

    // Phase 3: thread t reduces ALL 64 pixels of channel t (fp32 partials, as
    // verified in r6/r7; fp64 only at the atomics). Tile is 64 px -> one image row
    // half: gx = 64*(tile&1) + j, gy = tile>>1 (no row wrap: 64 | 128).
    float z = 0.f, sxl = 0.f;
    #pragma unroll
    for (int j = 0; j < 64; ++j) {
        float m = sm[t][j];        // bank (t+j)&31: 2-way, free
        z   += m;
        sxl  = fmaf(m, (float)j, sxl);
    }
    float gxb = (float)((tile & 1) << 6);
    float gy  = (float)(tile >> 1);
    int bk = b * KK + t;
    atomicAdd(&sxyz[bk * 3 + 0], (double)fmaf(gxb, z, sxl));
    atomicAdd(&sxyz[bk * 3 + 1], (double)(gy * z));
    atomicAdd(&sxyz[bk * 3 + 2], (double)z);
}

// ---------------- Keypoints: inclusive fp64 scan over flattened (b,k) ----------------
__global__ __launch_bounds__(256) void keypoint_k(const double* __restrict__ sxyz,
                                                  float* __restrict__ kp,
                                                  float* __restrict__ zeta) {
    const int PT = NBK / 256;   // 8
    int t = threadIdx.x;
    int lane = t & 63, wid = t >> 6;

    double vx[PT], vy[PT], vz[PT];
    double cx = 0.0, cy = 0.0;
    #pragma unroll
    for (int e = 0; e < PT; ++e) {
        int idx = t * PT + e;
        cx += sxyz[idx * 3 + 0]; vx[e] = cx;
        cy += sxyz[idx * 3 + 1]; vy[e] = cy;
        vz[e] = sxyz[idx * 3 + 2];
    }
    double tx = cx, ty = cy;
    for (int off = 1; off < 64; off <<= 1) {
        double ax = __shfl_up(tx, off, 64);
        double ay = __shfl_up(ty, off, 64);
        if (lane >= off) { tx += ax; ty += ay; }
    }
    __shared__ double wxs[4], wys[4];
    if (lane == 63) { wxs[wid] = tx; wys[wid] = ty; }
    __syncthreads();
    double offx = tx - cx, offy = ty - cy;
    for (int w2 = 0; w2 < wid; ++w2) { offx += wxs[w2]; offy += wys[w2]; }

    #pragma unroll
    for (int e = 0; e < PT; ++e) {
        int idx = t * PT + e;
        double zz = vz[e];
        double kx = rint((vx[e] + offx) / zz);
        double ky = rint((vy[e] + offy) / zz);
        float fkx = (float)kx, fky = (float)ky;
        if (fkx > 128.0f || fkx < 0.0f) fkx = 64.0f;   // PRE_WIDTH clamp -> center
        if (fky > 96.0f  || fky < 0.0f) fky = 48.0f;   // PRE_HEIGHT clamp -> center
        kp[idx * 2 + 0] = fkx;
        kp[idx * 2 + 1] = fky;
        zeta[idx] = (float)zz;
    }
}

extern "C" void kernel_launch(void* const* d_in, const int* in_sizes, int n_in,
                              void* d_out, int out_size, void* d_ws, size_t ws_size,
                              hipStream_t stream) {
    const float* x = (const float*)d_in[0];
    float* out  = (float*)d_out;
    float* map  = out;                         // [B,K,H,W]
    float* kp   = out + MAP_SIZE;              // [B,K,2]
    float* zeta = out + MAP_SIZE + NBK * 2;    // [B,K]
    double* sxyz = (double*)d_ws;              // [NBK][3] fp64 accumulators

    hipMemsetAsync(d_ws, 0, (size_t)NBK * 3 * sizeof(double), stream);
    fused_k   <<< NBLK, TK, 0, stream >>> (x, map, sxyz);
    keypoint_k<<< 1,    256, 0, stream >>> (sxyz, kp, zeta);
}

// Round 9
// 186.288 us; speedup vs baseline: 1.0527x; 1.0527x over previous
//
#include <hip/hip_runtime.h>
#include <math.h>

#define BB 32
#define KK 64
#define HH 96
#define WW 128
#define HW (HH*WW)             // 12288
#define MAP_SIZE (BB*KK*HW)    // 25165824
#define NBK (BB*KK)            // 2048
#define NT  (HW/256)           // 48 pixel-tiles per image
#define SST 259                // LDS row stride (floats): bank(3k+t) -> <=3-way everywhere

typedef const __attribute__((address_space(1))) float gfloat;
typedef __attribute__((address_space(3))) float lfloat;

// ---------------- Fused kernel: softmax + map write + per-(b,k) reductions ----------
// LOAD-DEPTH fix: phase 1 uses global_load_lds DMA (global -> LDS, no VGPR round
// trip, no per-iteration waitcnt). Each wave fires its 64 channel loads back-to-back
// -> 16 KB in flight per wave (~131 KB/CU), vs the ~10 KB/CU the compiler's
// load->exp->add pipeline exposed before (which Little's-law-matches the observed
// 2.7 TB/s plateau at ~900 cyc HBM latency). Everything after the DMA drain is the
// round-7 verified structure: exp in serial k-order from LDS (bit-identical den),
// NT map stores, LDS-staged fp32 transposed reduce, fp64 atomics.
__global__ __launch_bounds__(256, 2) void fused_k(const float* __restrict__ x,
                                                  float* __restrict__ out,
                                                  double* __restrict__ sxyz) {
    __shared__ float sm[KK][SST];

    int blk  = blockIdx.x;
    int b    = blk / NT;
    int tile = blk - b * NT;
    int t    = threadIdx.x;
    size_t base = (size_t)b * (KK * HW) + (size_t)tile * 256 + t;

    // Phase 1: 64 async DMA loads per wave, all in flight simultaneously.
    // LDS dest = wave-uniform row base + lane*4 (sm[k][64w..64w+64) contiguous);
    // global src is per-lane. One drain at the end instead of 64 partial waits.
    #pragma unroll
    for (int k = 0; k < KK; ++k) {
        __builtin_amdgcn_global_load_lds((gfloat*)(x + base + (size_t)k * HW),
                                         (lfloat*)&sm[k][t], 4, 0, 0);
    }
    asm volatile("s_waitcnt vmcnt(0)" ::: "memory");
    __builtin_amdgcn_sched_barrier(0);   // rule #18: no hoisting past the drain

    // Phase 2: exp own column in the same serial k-order as every passing round
    // (bit-identical den); stage e back to LDS. Own-column -> no cross-wave dep.
    float den = 0.f;
    #pragma unroll
    for (int k = 0; k < KK; ++k) {
        float e = __expf(sm[k][t]);
        sm[k][t] = e;
        den += e;
    }
    float inv = 1.f / den;

    // Phase 3: normalize own column, NT-store the map (streaming; nothing re-reads
    // it), stage normalized value for the transposed reduce.
    #pragma unroll
    for (int k = 0; k < KK; ++k) {
        float m = sm[k][t] * inv;
        __builtin_nontemporal_store(m, &out[base + (size_t)k * HW]);
        sm[k][t] = m;
    }
    __syncthreads();   // all columns staged for the cross-thread transpose

    // Phase 4: transposed reduction from LDS, fp32 (r6/r7-verified math, identical
    // summation order). Thread (k = t>>2, q = t&3) reduces 64 px of channel k.
    int k = t >> 2;
    int q = t & 3;
    const float gy_base = (float)(tile * 2);
    float z = 0.f, sx = 0.f, sy = 0.f;
    #pragma unroll
    for (int j = 0; j < 16; ++j) {
        int p0 = q * 4 + j * 16;                // p0..p0+3 share a row (no wrap)
        float m0 = sm[k][p0 + 0];
        float m1 = sm[k][p0 + 1];
        float m2 = sm[k][p0 + 2];
        float m3 = sm[k][p0 + 3];
        float s = (m0 + m1) + (m2 + m3);
        z  += s;
        sx += fmaf(s, (float)(p0 & (WW - 1)), fmaf(3.f, m3, fmaf(2.f, m2, m1)));
        sy += s * (gy_base + (float)(p0 >> 7));
    }

    // Combine the 4 lanes of each channel (lanes differ in bits 0-1 of lane id).
    z  += __shfl_xor(z,  1, 64);  z  += __shfl_xor(z,  2, 64);
    sx += __shfl_xor(sx, 1, 64);  sx += __shfl_xor(sx, 2, 64);
    sy += __shfl_xor(sy, 1, 64);  sy += __shfl_xor(sy, 2, 64);
    if (q == 0) {
        int bk = b * KK + k;
        atomicAdd(&sxyz[bk * 3 + 0], (double)sx);
        atomicAdd(&sxyz[bk * 3 + 1], (double)sy);
        atomicAdd(&sxyz[bk * 3 + 2], (double)z);
    }
}

// ---------------- Keypoints: inclusive fp64 scan over flattened (b,k) ----------------
__global__ __launch_bounds__(256) void keypoint_k(const double* __restrict__ sxyz,
                                                  float* __restrict__ kp,
                                                  float* __restrict__ zeta) {
    const int PT = NBK / 256;   // 8
    int t = threadIdx.x;
    int lane = t & 63, wid = t >> 6;

    double vx[PT], vy[PT], vz[PT];
    double cx = 0.0, cy = 0.0;
    #pragma unroll
    for (int e = 0; e < PT; ++e) {
        int idx = t * PT + e;
        cx += sxyz[idx * 3 + 0]; vx[e] = cx;
        cy += sxyz[idx * 3 + 1]; vy[e] = cy;
        vz[e] = sxyz[idx * 3 + 2];
    }
    double tx = cx, ty = cy;
    for (int off = 1; off < 64; off <<= 1) {
        double ax = __shfl_up(tx, off, 64);
        double ay = __shfl_up(ty, off, 64);
        if (lane >= off) { tx += ax; ty += ay; }
    }
    __shared__ double wxs[4], wys[4];
    if (lane == 63) { wxs[wid] = tx; wys[wid] = ty; }
    __syncthreads();
    double offx = tx - cx, offy = ty - cy;
    for (int w2 = 0; w2 < wid; ++w2) { offx += wxs[w2]; offy += wys[w2]; }

    #pragma unroll
    for (int e = 0; e < PT; ++e) {
        int idx = t * PT + e;
        double zz = vz[e];
        double kx = rint((vx[e] + offx) / zz);
        double ky = rint((vy[e] + offy) / zz);
        float fkx = (float)kx, fky = (float)ky;
        if (fkx > 128.0f || fkx < 0.0f) fkx = 64.0f;   // PRE_WIDTH clamp -> center
        if (fky > 96.0f  || fky < 0.0f) fky = 48.0f;   // PRE_HEIGHT clamp -> center
        kp[idx * 2 + 0] = fkx;
        kp[idx * 2 + 1] = fky;
        zeta[idx] = (float)zz;
    }
}

extern "C" void kernel_launch(void* const* d_in, const int* in_sizes, int n_in,
                              void* d_out, int out_size, void* d_ws, size_t ws_size,
                              hipStream_t stream) {
    const float* x = (const float*)d_in[0];
    float* out  = (float*)d_out;
    float* map  = out;                         // [B,K,H,W]
    float* kp   = out + MAP_SIZE;              // [B,K,2]
    float* zeta = out + MAP_SIZE + NBK * 2;    // [B,K]
    double* sxyz = (double*)d_ws;              // [NBK][3] fp64 accumulators

    hipMemsetAsync(d_ws, 0, (size_t)NBK * 3 * sizeof(double), stream);
    fused_k   <<< BB * NT, 256, 0, stream >>> (x, map, sxyz);
    keypoint_k<<< 1,       256, 0, stream >>> (sxyz, kp, zeta);
}